// Round 1
// baseline (1053.310 us; speedup 1.0000x reference)
//
#include <hip/hip_runtime.h>
#include <cmath>

#define BB 8
#define LL 512
#define HH 512
// out: (BB, 3*LL, 5*HH) fp32

// ---------------- K1: row/col bias terms ----------------
// which = p*2 + iscol; 6 * B * L dots of length 512, one wave each.
__global__ __launch_bounds__(256) void k1_terms(
    const float* __restrict__ A, const float* __restrict__ Bm, const float* __restrict__ C,
    const float* __restrict__ w0, const float* __restrict__ w1, const float* __restrict__ w2,
    float* __restrict__ rowterm, float* __restrict__ colterm) {
  int tid = threadIdx.x;
  int wave = blockIdx.x * 4 + (tid >> 6);
  int lane = tid & 63;
  int which = wave / (BB * LL);        // 0..5
  int rem   = wave % (BB * LL);
  int b = rem / LL, i = rem % LL;
  int p = which >> 1, iscol = which & 1;
  const float* src;
  if      (p == 0) src = iscol ? Bm : A;
  else if (p == 1) src = iscol ? C  : A;
  else             src = iscol ? C  : Bm;
  const float* wv = (p == 0 ? w0 : (p == 1 ? w1 : w2)) + (iscol ? HH : 0);
  const float* row = src + ((size_t)b * LL + i) * HH;
  float acc = 0.f;
#pragma unroll
  for (int t = 0; t < 8; ++t) acc += row[t * 64 + lane] * wv[t * 64 + lane];
#pragma unroll
  for (int off = 32; off; off >>= 1) acc += __shfl_xor(acc, off, 64);
  if (lane == 0) {
    float* dst = iscol ? colterm : rowterm;
    dst[(p * BB + b) * LL + i] = acc;
  }
}

// ---------------- K2: flash per-row attention ----------------
// One wave per (pair, b, i). Pass1: logits -> LDS + exact row max.
// Pass2: exp/accumulate o = sum_j p_j * Y_j. Writes a2b slice + X*a2b slice.
__global__ __launch_bounds__(256) void k2_flash(
    const float* __restrict__ A, const float* __restrict__ Bm, const float* __restrict__ C,
    const float* __restrict__ w0, const float* __restrict__ w1, const float* __restrict__ w2,
    const float* __restrict__ rowterm, const float* __restrict__ colterm,
    float* __restrict__ mrow, float* __restrict__ out) {
  __shared__ float s_sm[4][LL];
  int tid = threadIdx.x;
  int wv = tid >> 6, lane = tid & 63;
  int gw = blockIdx.x * 4 + wv;        // 0 .. 3*B*L-1
  int p = gw / (BB * LL);
  int rem = gw % (BB * LL);
  int b = rem / LL, i = rem % LL;
  const float *X, *Y, *wfull;
  if      (p == 0) { X = A;  Y = Bm; wfull = w0; }
  else if (p == 1) { X = A;  Y = C;  wfull = w1; }
  else             { X = Bm; Y = C;  wfull = w2; }
  const float* wm = wfull + 2 * HH;
  const float* xrow = X + ((size_t)b * LL + i) * HH;
  float q[8];
#pragma unroll
  for (int t = 0; t < 8; ++t) q[t] = xrow[t * 64 + lane] * wm[t * 64 + lane];
  float rt = rowterm[(p * BB + b) * LL + i];
  const float* Yb = Y + (size_t)b * LL * HH;
  const float* ct = colterm + (p * BB + b) * LL;
  float m = -1e30f;
  for (int j = 0; j < LL; ++j) {
    const float* yrow = Yb + j * HH;
    float acc = 0.f;
#pragma unroll
    for (int t = 0; t < 8; ++t) acc += q[t] * yrow[t * 64 + lane];
#pragma unroll
    for (int off = 32; off; off >>= 1) acc += __shfl_xor(acc, off, 64);
    float sj = acc + rt + ct[j];     // wave-uniform after reduction
    if (lane == 0) s_sm[wv][j] = sj;
    m = fmaxf(m, sj);
  }
  if (lane == 0) mrow[(p * BB + b) * LL + i] = m;
  float o[8] = {0, 0, 0, 0, 0, 0, 0, 0};
  float l = 0.f;
  for (int j = 0; j < LL; ++j) {
    float pj = __expf(s_sm[wv][j] - m);
    l += pj;
    const float* yrow = Yb + j * HH;
#pragma unroll
    for (int t = 0; t < 8; ++t) o[t] += pj * yrow[t * 64 + lane];
  }
  float inv = 1.f / l;
  size_t rowbase; int colbase;
  if      (p == 0) { rowbase = ((size_t)b * 1536 + i) * 2560;       colbase = 512;  }
  else if (p == 1) { rowbase = ((size_t)b * 1536 + i) * 2560;       colbase = 1024; }
  else             { rowbase = ((size_t)b * 1536 + 512 + i) * 2560; colbase = 1024; }
  int prodbase = colbase + 1024;
#pragma unroll
  for (int t = 0; t < 8; ++t) {
    float val = o[t] * inv;
    out[rowbase + colbase + t * 64 + lane] = val;
    out[rowbase + prodbase + t * 64 + lane] = xrow[t * 64 + lane] * val;
  }
}

// ---------------- K3: beta softmax + weighted row-sum ----------------
// One block per (pair, b). beta = softmax_i(mrow); vvec = sum_i beta_i X_i.
__global__ __launch_bounds__(256) void k3_beta(
    const float* __restrict__ A, const float* __restrict__ Bm,
    const float* __restrict__ mrow, float* __restrict__ vvec) {
  __shared__ float red[256];
  __shared__ float beta[LL];
  int pb = blockIdx.x;   // 0..23
  int p = pb / BB, b = pb % BB;
  int tid = threadIdx.x;
  const float* m = mrow + (p * BB + b) * LL;
  float m0 = fmaxf(m[tid], m[tid + 256]);
  red[tid] = m0;
  __syncthreads();
  for (int off = 128; off; off >>= 1) {
    if (tid < off) red[tid] = fmaxf(red[tid], red[tid + off]);
    __syncthreads();
  }
  float mx = red[0];
  __syncthreads();
  float e0 = __expf(m[tid] - mx), e1 = __expf(m[tid + 256] - mx);
  beta[tid] = e0; beta[tid + 256] = e1;
  red[tid] = e0 + e1;
  __syncthreads();
  for (int off = 128; off; off >>= 1) {
    if (tid < off) red[tid] += red[tid + off];
    __syncthreads();
  }
  float inv = 1.f / red[0];
  __syncthreads();
  const float* X = (p == 2) ? Bm : A;
  const float* Xb = X + (size_t)b * LL * HH;
  for (int dbase = 0; dbase < HH; dbase += 256) {
    int d = dbase + tid;
    float acc = 0.f;
    for (int i = 0; i < LL; ++i) acc += beta[i] * Xb[i * HH + d];
    vvec[(p * BB + b) * HH + d] = acc * inv;
  }
}

// ---------------- K4: finalize copies / broadcasts / products ----------------
__global__ __launch_bounds__(256) void k4_finalize(
    const float* __restrict__ A, const float* __restrict__ Bm, const float* __restrict__ C,
    const float* __restrict__ vvec, float* __restrict__ out) {
  size_t idx = (size_t)blockIdx.x * 256 + threadIdx.x;
  int c = (int)(idx % 2560);
  size_t r = idx / 2560;
  int row = (int)(r % 1536);
  int b = (int)(r / 1536);
  int sec = row / 512, i = row % 512;
  int slice = c / 512, cc = c % 512;
  // skip slices written by k2
  if (sec == 0 && slice != 0) return;
  if (sec == 1 && (slice == 2 || slice == 4)) return;
  const float* enc = sec == 0 ? A : (sec == 1 ? Bm : C);
  float e = enc[((size_t)b * LL + i) * HH + cc];
  float val;
  if (slice == 0) {
    val = e;
  } else if (sec == 1) {
    float v = vvec[(0 * BB + b) * HH + cc];       // b2a
    val = (slice == 1) ? v : e * v;
  } else {
    float v = (slice == 1 || slice == 3) ? vvec[(1 * BB + b) * HH + cc]   // c2a
                                         : vvec[(2 * BB + b) * HH + cc];  // c2b
    val = (slice <= 2) ? v : e * v;
  }
  out[idx] = val;
}

extern "C" void kernel_launch(void* const* d_in, const int* in_sizes, int n_in,
                              void* d_out, int out_size, void* d_ws, size_t ws_size,
                              hipStream_t stream) {
  const float* A  = (const float*)d_in[0];
  const float* Bm = (const float*)d_in[1];
  const float* C  = (const float*)d_in[2];
  const float* w0 = (const float*)d_in[3];
  const float* w1 = (const float*)d_in[4];
  const float* w2 = (const float*)d_in[5];
  float* out = (float*)d_out;
  float* ws = (float*)d_ws;
  float* rowterm = ws;              // 3*8*512
  float* colterm = ws + 12288;      // 3*8*512
  float* mrow    = ws + 24576;      // 3*8*512
  float* vvec    = ws + 36864;      // 3*8*512

  k1_terms<<<6144, 256, 0, stream>>>(A, Bm, C, w0, w1, w2, rowterm, colterm);
  k2_flash<<<3072, 256, 0, stream>>>(A, Bm, C, w0, w1, w2, rowterm, colterm, mrow, out);
  k3_beta<<<24, 256, 0, stream>>>(A, Bm, mrow, vvec);
  k4_finalize<<<122880, 256, 0, stream>>>(A, Bm, C, vvec, out);
}

// Round 2
// 364.593 us; speedup vs baseline: 2.8890x; 2.8890x over previous
//
#include <hip/hip_runtime.h>
#include <cmath>

#define BB 8
#define LL 512
#define HH 512

typedef __attribute__((ext_vector_type(8))) short short8;
typedef __attribute__((ext_vector_type(4))) float floatx4;

__device__ __forceinline__ unsigned short f2bf(float x) {
  unsigned int u = __float_as_uint(x);
  unsigned int r = (u + 0x7fffu + ((u >> 16) & 1u)) >> 16;
  return (unsigned short)r;
}
__device__ __forceinline__ float bf2f(unsigned short s) {
  return __uint_as_float(((unsigned int)s) << 16);
}

// ---------------- K1: row/col bias terms ----------------
__global__ __launch_bounds__(256) void k1_terms(
    const float* __restrict__ A, const float* __restrict__ Bm, const float* __restrict__ C,
    const float* __restrict__ w0, const float* __restrict__ w1, const float* __restrict__ w2,
    float* __restrict__ rowterm, float* __restrict__ colterm) {
  int tid = threadIdx.x;
  int wave = blockIdx.x * 4 + (tid >> 6);
  int lane = tid & 63;
  int which = wave / (BB * LL);
  int rem   = wave % (BB * LL);
  int b = rem / LL, i = rem % LL;
  int p = which >> 1, iscol = which & 1;
  const float* src;
  if      (p == 0) src = iscol ? Bm : A;
  else if (p == 1) src = iscol ? C  : A;
  else             src = iscol ? C  : Bm;
  const float* wv = (p == 0 ? w0 : (p == 1 ? w1 : w2)) + (iscol ? HH : 0);
  const float* row = src + ((size_t)b * LL + i) * HH;
  float acc = 0.f;
#pragma unroll
  for (int t = 0; t < 8; ++t) acc += row[t * 64 + lane] * wv[t * 64 + lane];
#pragma unroll
  for (int off = 32; off; off >>= 1) acc += __shfl_xor(acc, off, 64);
  if (lane == 0) {
    float* dst = iscol ? colterm : rowterm;
    dst[(p * BB + b) * LL + i] = acc;
  }
}

// ---------------- K2: fused MFMA pair-attention ----------------
// 32 query rows per block. Phase 1: S = (X.wM)@Y^T + rt + ct -> LDS bf16.
// Softmax (exact, full row in LDS) -> P bf16 in LDS, mrow, 1/l.
// Phase 2: O = P@Y via MFMA (Y transposed tile-staged), write out slices.
#define SD2 516   // S_lds stride (shorts), 258 dw == 2 mod 32
#define SD1 132   // Ystage stride (shorts), 66 dw == 2 mod 32

__global__ __launch_bounds__(256) void k2_mfma(
    const float* __restrict__ A, const float* __restrict__ Bm, const float* __restrict__ C,
    const float* __restrict__ w0, const float* __restrict__ w1, const float* __restrict__ w2,
    const float* __restrict__ rowterm, const float* __restrict__ colterm,
    float* __restrict__ mrow, float* __restrict__ out) {
  __shared__ unsigned short S_lds[32 * SD2];
  __shared__ unsigned short Yst[128 * SD1];
  __shared__ float ct_lds[512];
  __shared__ float rt_lds[32];
  __shared__ float rinv_lds[32];

  int tid = threadIdx.x;
  int bid = blockIdx.x;
  int p = bid >> 7;
  int rem = bid & 127;
  int b = rem >> 4;
  int rb = rem & 15;

  const float *X, *Y, *wfull;
  if      (p == 0) { X = A;  Y = Bm; wfull = w0; }
  else if (p == 1) { X = A;  Y = C;  wfull = w1; }
  else             { X = Bm; Y = C;  wfull = w2; }

  {
    const float* ct = colterm + (p * BB + b) * LL;
    ct_lds[tid] = ct[tid];
    ct_lds[tid + 256] = ct[tid + 256];
    if (tid < 32) rt_lds[tid] = rowterm[(p * BB + b) * LL + rb * 32 + tid];
  }

  int w = tid >> 6, lane = tid & 63;
  int wr = w >> 1, wc = w & 1;
  int n16 = lane & 15, q = lane >> 4;

  // A-fragments (X .* wM), rows rb*32 + wr*16 + n16, all 512 k, bf16 in regs
  short8 af[16];
  {
    int irow = rb * 32 + wr * 16 + n16;
    const float* xr = X + ((size_t)(b * LL + irow)) * HH;
    const float* wm = wfull + 2 * HH;
#pragma unroll
    for (int kk = 0; kk < 16; ++kk) {
      int k0 = kk * 32 + q * 8;
      short8 v;
#pragma unroll
      for (int e = 0; e < 8; ++e) v[e] = (short)f2bf(xr[k0 + e] * wm[k0 + e]);
      af[kk] = v;
    }
  }

  const float* Yb = Y + (size_t)b * LL * HH;

  // ---- Phase 1: S tile ----
#pragma unroll 1
  for (int jt = 0; jt < 4; ++jt) {
    floatx4 acc[4] = {};
#pragma unroll 1
    for (int kt = 0; kt < 4; ++kt) {
      __syncthreads();
      {
        int jl0 = tid >> 4;
        int k0 = (tid & 15) * 8;
#pragma unroll
        for (int i = 0; i < 8; ++i) {
          int jl = i * 16 + jl0;
          const float* src = Yb + (size_t)(jt * 128 + jl) * HH + kt * 128 + k0;
          unsigned short* dst = &Yst[jl * SD1 + k0];
#pragma unroll
          for (int e = 0; e < 8; ++e) dst[e] = f2bf(src[e]);
        }
      }
      __syncthreads();
#pragma unroll
      for (int kc = 0; kc < 4; ++kc) {
        short8 a = af[kt * 4 + kc];
#pragma unroll
        for (int f = 0; f < 4; ++f) {
          const unsigned short* bp = &Yst[(wc * 64 + f * 16 + n16) * SD1 + kc * 32 + q * 8];
          short8 bb;
#pragma unroll
          for (int e = 0; e < 8; ++e) bb[e] = (short)bp[e];
          acc[f] = __builtin_amdgcn_mfma_f32_16x16x32_bf16(a, bb, acc[f], 0, 0, 0);
        }
      }
    }
#pragma unroll
    for (int f = 0; f < 4; ++f) {
      int col = jt * 128 + wc * 64 + f * 16 + n16;
      float ctv = ct_lds[col];
#pragma unroll
      for (int r = 0; r < 4; ++r) {
        int row = wr * 16 + q * 4 + r;
        float val = acc[f][r] + rt_lds[row] + ctv;
        S_lds[row * SD2 + col] = f2bf(val);
      }
    }
  }

  // ---- Softmax (exact) ----
  __syncthreads();
  {
    int r = tid >> 3, c8 = tid & 7;
    unsigned short* srow = &S_lds[r * SD2];
    float mx = -1e30f;
#pragma unroll
    for (int s = 0; s < 64; ++s) mx = fmaxf(mx, bf2f(srow[s * 8 + c8]));
    mx = fmaxf(mx, __shfl_xor(mx, 1, 64));
    mx = fmaxf(mx, __shfl_xor(mx, 2, 64));
    mx = fmaxf(mx, __shfl_xor(mx, 4, 64));
    float lsum = 0.f;
#pragma unroll
    for (int s = 0; s < 64; ++s) {
      float sv = bf2f(srow[s * 8 + c8]);
      float pv = __expf(sv - mx);
      lsum += pv;
      srow[s * 8 + c8] = f2bf(pv);
    }
    lsum += __shfl_xor(lsum, 1, 64);
    lsum += __shfl_xor(lsum, 2, 64);
    lsum += __shfl_xor(lsum, 4, 64);
    if (c8 == 0) {
      rinv_lds[r] = 1.f / lsum;
      mrow[(p * BB + b) * LL + rb * 32 + r] = mx;
    }
  }

  // ---- Phase 2: O = P @ Y ----
  int secoff, colbase;
  if      (p == 0) { secoff = 0;   colbase = 512;  }
  else if (p == 1) { secoff = 0;   colbase = 1024; }
  else             { secoff = 512; colbase = 1024; }

#pragma unroll 1
  for (int dc = 0; dc < 4; ++dc) {
    floatx4 oacc[4] = {};
#pragma unroll 1
    for (int jtile = 0; jtile < 4; ++jtile) {
      __syncthreads();
      {
        int jl0 = tid >> 4;
        int d0 = (tid & 15) * 8;
#pragma unroll
        for (int i = 0; i < 8; ++i) {
          int jl = i * 16 + jl0;
          const float* src = Yb + (size_t)(jtile * 128 + jl) * HH + dc * 128 + d0;
#pragma unroll
          for (int e = 0; e < 8; ++e)
            Yst[(d0 + e) * SD1 + jl] = f2bf(src[e]);   // transposed: [d][j]
        }
      }
      __syncthreads();
#pragma unroll
      for (int kc = 0; kc < 4; ++kc) {
        const unsigned short* ap = &S_lds[(wr * 16 + n16) * SD2 + jtile * 128 + kc * 32 + q * 8];
        short8 a;
#pragma unroll
        for (int e = 0; e < 8; ++e) a[e] = (short)ap[e];
#pragma unroll
        for (int f = 0; f < 4; ++f) {
          const unsigned short* bp = &Yst[(wc * 64 + f * 16 + n16) * SD1 + kc * 32 + q * 8];
          short8 bb;
#pragma unroll
          for (int e = 0; e < 8; ++e) bb[e] = (short)bp[e];
          oacc[f] = __builtin_amdgcn_mfma_f32_16x16x32_bf16(a, bb, oacc[f], 0, 0, 0);
        }
      }
    }
#pragma unroll
    for (int f = 0; f < 4; ++f) {
      int d = dc * 128 + wc * 64 + f * 16 + n16;
#pragma unroll
      for (int r = 0; r < 4; ++r) {
        int row = wr * 16 + q * 4 + r;
        int ig = rb * 32 + row;
        float val = oacc[f][r] * rinv_lds[row];
        size_t ob = ((size_t)b * 1536 + secoff + ig) * 2560;
        out[ob + colbase + d] = val;
        float xv = X[((size_t)b * LL + ig) * HH + d];
        out[ob + colbase + 1024 + d] = xv * val;
      }
    }
  }
}

// ---------------- K3: beta softmax + weighted row-sum ----------------
__global__ __launch_bounds__(256) void k3_beta(
    const float* __restrict__ A, const float* __restrict__ Bm,
    const float* __restrict__ mrow, float* __restrict__ vvec) {
  __shared__ float red[256];
  __shared__ float beta[LL];
  int pb = blockIdx.x;
  int p = pb / BB, b = pb % BB;
  int tid = threadIdx.x;
  const float* m = mrow + (p * BB + b) * LL;
  float m0 = fmaxf(m[tid], m[tid + 256]);
  red[tid] = m0;
  __syncthreads();
  for (int off = 128; off; off >>= 1) {
    if (tid < off) red[tid] = fmaxf(red[tid], red[tid + off]);
    __syncthreads();
  }
  float mx = red[0];
  __syncthreads();
  float e0 = __expf(m[tid] - mx), e1 = __expf(m[tid + 256] - mx);
  beta[tid] = e0; beta[tid + 256] = e1;
  red[tid] = e0 + e1;
  __syncthreads();
  for (int off = 128; off; off >>= 1) {
    if (tid < off) red[tid] += red[tid + off];
    __syncthreads();
  }
  float inv = 1.f / red[0];
  __syncthreads();
  const float* X = (p == 2) ? Bm : A;
  const float* Xb = X + (size_t)b * LL * HH;
  for (int dbase = 0; dbase < HH; dbase += 256) {
    int d = dbase + tid;
    float acc = 0.f;
    for (int i = 0; i < LL; ++i) acc += beta[i] * Xb[i * HH + d];
    vvec[(p * BB + b) * HH + d] = acc * inv;
  }
}

// ---------------- K4: finalize copies / broadcasts / products ----------------
__global__ __launch_bounds__(256) void k4_finalize(
    const float* __restrict__ A, const float* __restrict__ Bm, const float* __restrict__ C,
    const float* __restrict__ vvec, float* __restrict__ out) {
  size_t idx = (size_t)blockIdx.x * 256 + threadIdx.x;
  int c = (int)(idx % 2560);
  size_t r = idx / 2560;
  int row = (int)(r % 1536);
  int b = (int)(r / 1536);
  int sec = row / 512, i = row % 512;
  int slice = c / 512, cc = c % 512;
  if (sec == 0 && slice != 0) return;
  if (sec == 1 && (slice == 2 || slice == 4)) return;
  const float* enc = sec == 0 ? A : (sec == 1 ? Bm : C);
  float e = enc[((size_t)b * LL + i) * HH + cc];
  float val;
  if (slice == 0) {
    val = e;
  } else if (sec == 1) {
    float v = vvec[(0 * BB + b) * HH + cc];
    val = (slice == 1) ? v : e * v;
  } else {
    float v = (slice == 1 || slice == 3) ? vvec[(1 * BB + b) * HH + cc]
                                         : vvec[(2 * BB + b) * HH + cc];
    val = (slice <= 2) ? v : e * v;
  }
  out[idx] = val;
}

extern "C" void kernel_launch(void* const* d_in, const int* in_sizes, int n_in,
                              void* d_out, int out_size, void* d_ws, size_t ws_size,
                              hipStream_t stream) {
  const float* A  = (const float*)d_in[0];
  const float* Bm = (const float*)d_in[1];
  const float* C  = (const float*)d_in[2];
  const float* w0 = (const float*)d_in[3];
  const float* w1 = (const float*)d_in[4];
  const float* w2 = (const float*)d_in[5];
  float* out = (float*)d_out;
  float* ws = (float*)d_ws;
  float* rowterm = ws;
  float* colterm = ws + 12288;
  float* mrow    = ws + 24576;
  float* vvec    = ws + 36864;

  k1_terms<<<6144, 256, 0, stream>>>(A, Bm, C, w0, w1, w2, rowterm, colterm);
  k2_mfma<<<384, 256, 0, stream>>>(A, Bm, C, w0, w1, w2, rowterm, colterm, mrow, out);
  k3_beta<<<24, 256, 0, stream>>>(A, Bm, mrow, vvec);
  k4_finalize<<<122880, 256, 0, stream>>>(A, Bm, C, vvec, out);
}

// Round 4
// 320.259 us; speedup vs baseline: 3.2889x; 1.1384x over previous
//
#include <hip/hip_runtime.h>
#include <cmath>

#define BB 8
#define LL 512
#define HH 512

typedef __attribute__((ext_vector_type(8))) short short8;
typedef __attribute__((ext_vector_type(4))) float floatx4;

__device__ __forceinline__ unsigned short f2bf(float x) {
  unsigned int u = __float_as_uint(x);
  unsigned int r = (u + 0x7fffu + ((u >> 16) & 1u)) >> 16;
  return (unsigned short)r;
}

// ---------------- K0a: convert Bm,C to bf16, normal + transposed ----------------
__global__ __launch_bounds__(256) void k0_conv(
    const float* __restrict__ Bm, const float* __restrict__ C,
    unsigned short* __restrict__ Bn, unsigned short* __restrict__ Cn,
    unsigned short* __restrict__ Bt, unsigned short* __restrict__ Ct) {
  __shared__ unsigned short tile[64][68];
  int bid = blockIdx.x;            // 1024
  int s = bid >> 9;
  int rem = bid & 511;
  int b = rem >> 6, tr = (rem >> 3) & 7, tc = rem & 7;
  const float* src = s ? C : Bm;
  unsigned short* dn = s ? Cn : Bn;
  unsigned short* dt = s ? Ct : Bt;
  int t = threadIdx.x;
  int r0 = t >> 4, c0 = (t & 15) * 4;
#pragma unroll
  for (int rr = 0; rr < 4; ++rr) {
    int r = rr * 16 + r0;
    const float* sp = src + ((size_t)(b * 512 + tr * 64 + r)) * 512 + tc * 64 + c0;
    float4 v = *(const float4*)sp;
    unsigned short h0 = f2bf(v.x), h1 = f2bf(v.y), h2 = f2bf(v.z), h3 = f2bf(v.w);
    unsigned short* np = dn + ((size_t)(b * 512 + tr * 64 + r)) * 512 + tc * 64 + c0;
    np[0] = h0; np[1] = h1; np[2] = h2; np[3] = h3;
    tile[r][c0] = h0; tile[r][c0 + 1] = h1; tile[r][c0 + 2] = h2; tile[r][c0 + 3] = h3;
  }
  __syncthreads();
  int d = t & 63, j0 = (t >> 6) * 16;
  short8 v0, v1;
#pragma unroll
  for (int e = 0; e < 8; ++e) v0[e] = (short)tile[j0 + e][d];
#pragma unroll
  for (int e = 0; e < 8; ++e) v1[e] = (short)tile[j0 + 8 + e][d];
  unsigned short* tp = dt + ((size_t)(b * 512 + tc * 64 + d)) * 512 + tr * 64 + j0;
  *(short8*)tp = v0;
  *(short8*)(tp + 8) = v1;
}

// ---------------- K0b: Xm_p = bf16(X .* wM_p) ----------------
__global__ __launch_bounds__(256) void k0_xm(
    const float* __restrict__ A, const float* __restrict__ Bm,
    const float* __restrict__ w0, const float* __restrict__ w1, const float* __restrict__ w2,
    unsigned short* __restrict__ Xm0, unsigned short* __restrict__ Xm1,
    unsigned short* __restrict__ Xm2) {
  unsigned int idx = blockIdx.x * 256 + threadIdx.x;   // 786432 threads
  size_t e0 = (size_t)idx * 8;
  int k0 = (int)(e0 & 511);
  unsigned int ri = (unsigned int)(e0 >> 9);  // p*4096 + b*512 + i
  int p = ri >> 12;
  unsigned int rowi = ri & 4095;
  const float* X = (p == 2) ? Bm : A;
  const float* wm = ((p == 0) ? w0 : (p == 1) ? w1 : w2) + 2 * HH;
  const float* xp = X + (size_t)rowi * 512 + k0;
  float4 a = *(const float4*)xp, b4 = *(const float4*)(xp + 4);
  float4 wa = *(const float4*)(wm + k0), wb = *(const float4*)(wm + k0 + 4);
  short8 o;
  o[0] = (short)f2bf(a.x * wa.x); o[1] = (short)f2bf(a.y * wa.y);
  o[2] = (short)f2bf(a.z * wa.z); o[3] = (short)f2bf(a.w * wa.w);
  o[4] = (short)f2bf(b4.x * wb.x); o[5] = (short)f2bf(b4.y * wb.y);
  o[6] = (short)f2bf(b4.z * wb.z); o[7] = (short)f2bf(b4.w * wb.w);
  unsigned short* op = ((p == 0) ? Xm0 : (p == 1) ? Xm1 : Xm2) + (size_t)rowi * 512 + k0;
  *(short8*)op = o;
}

// ---------------- K1: row/col bias terms (each row read once, 2 dots) ----------------
__global__ __launch_bounds__(256) void k1_terms(
    const float* __restrict__ A, const float* __restrict__ Bm, const float* __restrict__ C,
    const float* __restrict__ w0, const float* __restrict__ w1, const float* __restrict__ w2,
    float* __restrict__ rowterm, float* __restrict__ colterm) {
  int tid = threadIdx.x;
  int wave = blockIdx.x * 4 + (tid >> 6);   // 0..12287
  int lane = tid & 63;
  int m = wave >> 12;
  int rem = wave & 4095;
  int b = rem >> 9, i = rem & 511;
  const float* src = (m == 0) ? A : (m == 1 ? Bm : C);
  const float *wva, *wvb;
  float *da, *db;
  if (m == 0) {
    wva = w0;      wvb = w1;
    da = rowterm + (0 * BB + b) * LL + i;  db = rowterm + (1 * BB + b) * LL + i;
  } else if (m == 1) {
    wva = w0 + HH; wvb = w2;
    da = colterm + (0 * BB + b) * LL + i;  db = rowterm + (2 * BB + b) * LL + i;
  } else {
    wva = w1 + HH; wvb = w2 + HH;
    da = colterm + (1 * BB + b) * LL + i;  db = colterm + (2 * BB + b) * LL + i;
  }
  const float* row = src + ((size_t)b * LL + i) * HH;
  float a1 = 0.f, a2 = 0.f;
#pragma unroll
  for (int t = 0; t < 8; ++t) {
    float x = row[t * 64 + lane];
    a1 += x * wva[t * 64 + lane];
    a2 += x * wvb[t * 64 + lane];
  }
#pragma unroll
  for (int off = 32; off; off >>= 1) {
    a1 += __shfl_xor(a1, off, 64);
    a2 += __shfl_xor(a2, off, 64);
  }
  if (lane == 0) { *da = a1; *db = a2; }
}

// ---------------- K2: fused MFMA pair-attention, direct global fragments ----------------
// 32 rows/block, 384 blocks. S in registers; softmax with cross-wave (wc) LDS
// exchange of per-half max/sum; P via 32KB LDS (XOR-swizzled 16B chunks).
__global__ __launch_bounds__(256) void k2_mfma(
    const unsigned short* __restrict__ Xm0, const unsigned short* __restrict__ Xm1,
    const unsigned short* __restrict__ Xm2,
    const unsigned short* __restrict__ Bn, const unsigned short* __restrict__ Cn,
    const unsigned short* __restrict__ Bt, const unsigned short* __restrict__ Ct,
    const float* __restrict__ A, const float* __restrict__ Bm,
    const float* __restrict__ rowterm, const float* __restrict__ colterm,
    float* __restrict__ mrow, float* __restrict__ out) {
  __shared__ unsigned short P_lds[32 * 512];
  __shared__ float sm_m[64];
  __shared__ float sm_l[64];

  int tid = threadIdx.x;
  int bid = blockIdx.x;
  int p = bid >> 7;
  int rem = bid & 127;
  int b = rem >> 4;
  int rb = rem & 15;
  int i0 = rb * 32;

  const unsigned short* Xmp = (p == 0) ? Xm0 : ((p == 1) ? Xm1 : Xm2);
  const unsigned short* Yn  = (p == 0) ? Bn : Cn;
  const unsigned short* Yt  = (p == 0) ? Bt : Ct;
  const float* X = (p == 2) ? Bm : A;

  int w = tid >> 6, lane = tid & 63;
  int wr = w >> 1, wc = w & 1;
  int n16 = lane & 15, q = lane >> 4;

  int arow = i0 + wr * 16 + n16;
  const unsigned short* ap = Xmp + ((size_t)(b * LL + arow)) * HH;

  floatx4 acc[4][4] = {};

  // ---- Phase 1: S = Xm @ Yn^T ----
#pragma unroll 1
  for (int kt = 0; kt < 4; ++kt) {
    short8 af[4];
#pragma unroll
    for (int kc = 0; kc < 4; ++kc)
      af[kc] = *(const short8*)(ap + kt * 128 + kc * 32 + q * 8);
#pragma unroll
    for (int kc = 0; kc < 4; ++kc) {
      int k0 = kt * 128 + kc * 32 + q * 8;
#pragma unroll
      for (int jt = 0; jt < 4; ++jt) {
#pragma unroll
        for (int f = 0; f < 4; ++f) {
          int col = jt * 128 + wc * 64 + f * 16 + n16;
          short8 bf = *(const short8*)(Yn + ((size_t)(b * LL + col)) * HH + k0);
          acc[jt][f] = __builtin_amdgcn_mfma_f32_16x16x32_bf16(af[kc], bf, acc[jt][f], 0, 0, 0);
        }
      }
    }
  }

  // ---- Softmax: per-wave half-row stats + cross-wave (wc) combine via LDS ----
  float rt[4], rinv[4], ctv[4][4], mh[4], ml[4];
  {
    const float* rtp = rowterm + (p * BB + b) * LL + i0 + wr * 16 + q * 4;
#pragma unroll
    for (int r = 0; r < 4; ++r) rt[r] = rtp[r];
    const float* ctp = colterm + (p * BB + b) * LL;
#pragma unroll
    for (int jt = 0; jt < 4; ++jt)
#pragma unroll
      for (int f = 0; f < 4; ++f)
        ctv[jt][f] = ctp[jt * 128 + wc * 64 + f * 16 + n16];
  }
#pragma unroll
  for (int r = 0; r < 4; ++r) {
    float m = -1e30f;
#pragma unroll
    for (int jt = 0; jt < 4; ++jt)
#pragma unroll
      for (int f = 0; f < 4; ++f) {
        float v = acc[jt][f][r] + rt[r] + ctv[jt][f];
        acc[jt][f][r] = v;
        m = fmaxf(m, v);
      }
    m = fmaxf(m, __shfl_xor(m, 1, 64));
    m = fmaxf(m, __shfl_xor(m, 2, 64));
    m = fmaxf(m, __shfl_xor(m, 4, 64));
    m = fmaxf(m, __shfl_xor(m, 8, 64));
    mh[r] = m;
  }
  if (n16 == 0) {
#pragma unroll
    for (int r = 0; r < 4; ++r) sm_m[wc * 32 + wr * 16 + q * 4 + r] = mh[r];
  }
  __syncthreads();
#pragma unroll
  for (int r = 0; r < 4; ++r) {
    float m = fmaxf(mh[r], sm_m[(1 - wc) * 32 + wr * 16 + q * 4 + r]);
    mh[r] = m;
    float l = 0.f;
#pragma unroll
    for (int jt = 0; jt < 4; ++jt)
#pragma unroll
      for (int f = 0; f < 4; ++f) {
        float pv = __expf(acc[jt][f][r] - m);
        acc[jt][f][r] = pv;
        l += pv;
      }
    l += __shfl_xor(l, 1, 64);
    l += __shfl_xor(l, 2, 64);
    l += __shfl_xor(l, 4, 64);
    l += __shfl_xor(l, 8, 64);
    ml[r] = l;
  }
  if (n16 == 0) {
#pragma unroll
    for (int r = 0; r < 4; ++r) sm_l[wc * 32 + wr * 16 + q * 4 + r] = ml[r];
  }
  __syncthreads();
#pragma unroll
  for (int r = 0; r < 4; ++r) {
    float lf = ml[r] + sm_l[(1 - wc) * 32 + wr * 16 + q * 4 + r];
    rinv[r] = 1.f / lf;
    if (n16 == 0 && wc == 0)
      mrow[(p * BB + b) * LL + i0 + wr * 16 + q * 4 + r] = mh[r];
  }

  // ---- P -> LDS (bf16, unnormalized, XOR-swizzled 8-short chunks) ----
#pragma unroll
  for (int jt = 0; jt < 4; ++jt)
#pragma unroll
    for (int f = 0; f < 4; ++f) {
      int c = jt * 16 + wc * 8 + f * 2 + (n16 >> 3);
#pragma unroll
      for (int r = 0; r < 4; ++r) {
        int row = wr * 16 + q * 4 + r;
        int pc = c ^ (row & 7);
        P_lds[row * 512 + pc * 8 + (n16 & 7)] = f2bf(acc[jt][f][r]);
      }
    }
  __syncthreads();

  // ---- Phase 2: O = P @ Y (B from Yt) ----
  int secoff, colbase;
  if      (p == 0) { secoff = 0;   colbase = 512;  }
  else if (p == 1) { secoff = 0;   colbase = 1024; }
  else             { secoff = 512; colbase = 1024; }

  int prow = wr * 16 + n16;
#pragma unroll 1
  for (int dc = 0; dc < 4; ++dc) {
    floatx4 oacc[4] = {};
#pragma unroll 1
    for (int jt = 0; jt < 4; ++jt) {
#pragma unroll
      for (int kc = 0; kc < 4; ++kc) {
        int c = jt * 16 + kc * 4 + q;
        int pc = c ^ (prow & 7);
        short8 a = *(const short8*)&P_lds[prow * 512 + pc * 8];
        int j0 = jt * 128 + kc * 32 + q * 8;
#pragma unroll
        for (int f = 0; f < 4; ++f) {
          int d = dc * 128 + wc * 64 + f * 16 + n16;
          short8 bf = *(const short8*)(Yt + ((size_t)(b * LL + d)) * HH + j0);
          oacc[f] = __builtin_amdgcn_mfma_f32_16x16x32_bf16(a, bf, oacc[f], 0, 0, 0);
        }
      }
    }
#pragma unroll
    for (int f = 0; f < 4; ++f) {
      int d = dc * 128 + wc * 64 + f * 16 + n16;
#pragma unroll
      for (int r = 0; r < 4; ++r) {
        int ig = i0 + wr * 16 + q * 4 + r;
        float val = oacc[f][r] * rinv[r];
        size_t ob = ((size_t)b * 1536 + secoff + ig) * 2560;
        out[ob + colbase + d] = val;
        out[ob + colbase + 1024 + d] = X[((size_t)b * LL + ig) * HH + d] * val;
      }
    }
  }
}

// ---------------- K3: beta softmax + weighted row-sum (192 blocks) ----------------
__global__ __launch_bounds__(256) void k3_beta(
    const float* __restrict__ A, const float* __restrict__ Bm,
    const float* __restrict__ mrow, float* __restrict__ vvec) {
  __shared__ float red[256];
  __shared__ float beta[LL];
  __shared__ float s_inv;
  int blk = blockIdx.x;           // 192
  int p = blk >> 6;
  int rem2 = blk & 63;
  int b = rem2 >> 3;
  int dch = rem2 & 7;
  int tid = threadIdx.x;
  const float* m = mrow + (p * BB + b) * LL;
  red[tid] = fmaxf(m[tid], m[tid + 256]);
  __syncthreads();
  for (int off = 128; off; off >>= 1) {
    if (tid < off) red[tid] = fmaxf(red[tid], red[tid + off]);
    __syncthreads();
  }
  float mx = red[0];
  __syncthreads();
  float e0 = __expf(m[tid] - mx), e1 = __expf(m[tid + 256] - mx);
  beta[tid] = e0; beta[tid + 256] = e1;
  red[tid] = e0 + e1;
  __syncthreads();
  for (int off = 128; off; off >>= 1) {
    if (tid < off) red[tid] += red[tid + off];
    __syncthreads();
  }
  if (tid == 0) s_inv = 1.f / red[0];
  __syncthreads();
  const float* Xb = ((p == 2) ? Bm : A) + (size_t)b * LL * HH;
  int d = dch * 64 + (tid & 63);
  int ig = tid >> 6;
  float acc = 0.f;
  for (int i = ig * 128; i < ig * 128 + 128; ++i)
    acc += beta[i] * Xb[(size_t)i * HH + d];
  red[tid] = acc;
  __syncthreads();
  if (tid < 64) {
    float s = red[tid] + red[tid + 64] + red[tid + 128] + red[tid + 192];
    vvec[(p * BB + b) * HH + dch * 64 + tid] = s * s_inv;
  }
}

// ---------------- K4: finalize, float4, only needed slices ----------------
__global__ __launch_bounds__(256) void k4_finalize(
    const float* __restrict__ A, const float* __restrict__ Bm, const float* __restrict__ C,
    const float* __restrict__ vvec, float* __restrict__ out) {
  unsigned int idx = blockIdx.x * 256 + threadIdx.x;   // 4718592 threads
  int f4 = idx & 127;
  int i  = (idx >> 7) & 511;
  unsigned int ub = idx >> 16;
  unsigned int u = ub % 9;
  unsigned int b = ub / 9;
  int sec, slice;
  if (u == 0)      { sec = 0; slice = 0; }
  else if (u <= 3) { sec = 1; slice = (u == 1) ? 0 : (u == 2 ? 1 : 3); }
  else             { sec = 2; slice = (int)u - 4; }
  int cc = f4 * 4;
  const float* enc = sec == 0 ? A : (sec == 1 ? Bm : C);
  float4 e = *(const float4*)(enc + ((size_t)b * LL + i) * HH + cc);
  float4 val;
  if (slice == 0) val = e;
  else {
    int vp = (sec == 1) ? 0 : ((slice == 1 || slice == 3) ? 1 : 2);
    float4 v = *(const float4*)(vvec + (vp * BB + b) * HH + cc);
    if (slice <= 2) val = v;
    else { val.x = e.x * v.x; val.y = e.y * v.y; val.z = e.z * v.z; val.w = e.w * v.w; }
  }
  *(float4*)(out + ((size_t)b * 1536 + sec * 512 + i) * 2560 + slice * 512 + cc) = val;
}

extern "C" void kernel_launch(void* const* d_in, const int* in_sizes, int n_in,
                              void* d_out, int out_size, void* d_ws, size_t ws_size,
                              hipStream_t stream) {
  const float* A  = (const float*)d_in[0];
  const float* Bm = (const float*)d_in[1];
  const float* C  = (const float*)d_in[2];
  const float* w0 = (const float*)d_in[3];
  const float* w1 = (const float*)d_in[4];
  const float* w2 = (const float*)d_in[5];
  float* out = (float*)d_out;

  float* wsf = (float*)d_ws;
  float* rowterm = wsf;
  float* colterm = wsf + 12288;
  float* mrow    = wsf + 24576;
  float* vvec    = wsf + 36864;
  unsigned short* wss = (unsigned short*)(wsf + 49152);
  const size_t MSZ = (size_t)BB * LL * HH;     // 2,097,152
  unsigned short* Bn  = wss;
  unsigned short* Cn  = wss + MSZ;
  unsigned short* Bt  = wss + 2 * MSZ;
  unsigned short* Ct  = wss + 3 * MSZ;
  unsigned short* Xm0 = wss + 4 * MSZ;
  unsigned short* Xm1 = wss + 5 * MSZ;
  unsigned short* Xm2 = wss + 6 * MSZ;

  k0_conv<<<1024, 256, 0, stream>>>(Bm, C, Bn, Cn, Bt, Ct);
  k0_xm<<<3072, 256, 0, stream>>>(A, Bm, w0, w1, w2, Xm0, Xm1, Xm2);
  k1_terms<<<3072, 256, 0, stream>>>(A, Bm, C, w0, w1, w2, rowterm, colterm);
  k2_mfma<<<384, 256, 0, stream>>>(Xm0, Xm1, Xm2, Bn, Cn, Bt, Ct, A, Bm,
                                   rowterm, colterm, mrow, out);
  k3_beta<<<192, 256, 0, stream>>>(A, Bm, mrow, vvec);
  k4_finalize<<<18432, 256, 0, stream>>>(A, Bm, C, vvec, out);
}

// Round 5
// 302.895 us; speedup vs baseline: 3.4775x; 1.0573x over previous
//
#include <hip/hip_runtime.h>
#include <cmath>

#define BB 8
#define LL 512
#define HH 512

typedef __attribute__((ext_vector_type(8))) short short8;
typedef __attribute__((ext_vector_type(4))) float floatx4;

__device__ __forceinline__ unsigned short f2bf(float x) {
  unsigned int u = __float_as_uint(x);
  unsigned int r = (u + 0x7fffu + ((u >> 16) & 1u)) >> 16;
  return (unsigned short)r;
}

// ---------------- K0a: convert Bm,C to bf16, normal + transposed ----------------
__global__ __launch_bounds__(256) void k0_conv(
    const float* __restrict__ Bm, const float* __restrict__ C,
    unsigned short* __restrict__ Bn, unsigned short* __restrict__ Cn,
    unsigned short* __restrict__ Bt, unsigned short* __restrict__ Ct) {
  __shared__ unsigned short tile[64][68];
  int bid = blockIdx.x;            // 1024
  int s = bid >> 9;
  int rem = bid & 511;
  int b = rem >> 6, tr = (rem >> 3) & 7, tc = rem & 7;
  const float* src = s ? C : Bm;
  unsigned short* dn = s ? Cn : Bn;
  unsigned short* dt = s ? Ct : Bt;
  int t = threadIdx.x;
  int r0 = t >> 4, c0 = (t & 15) * 4;
#pragma unroll
  for (int rr = 0; rr < 4; ++rr) {
    int r = rr * 16 + r0;
    const float* sp = src + ((size_t)(b * 512 + tr * 64 + r)) * 512 + tc * 64 + c0;
    float4 v = *(const float4*)sp;
    unsigned short h0 = f2bf(v.x), h1 = f2bf(v.y), h2 = f2bf(v.z), h3 = f2bf(v.w);
    unsigned short* np = dn + ((size_t)(b * 512 + tr * 64 + r)) * 512 + tc * 64 + c0;
    np[0] = h0; np[1] = h1; np[2] = h2; np[3] = h3;
    tile[r][c0] = h0; tile[r][c0 + 1] = h1; tile[r][c0 + 2] = h2; tile[r][c0 + 3] = h3;
  }
  __syncthreads();
  int d = t & 63, j0 = (t >> 6) * 16;
  short8 v0, v1;
#pragma unroll
  for (int e = 0; e < 8; ++e) v0[e] = (short)tile[j0 + e][d];
#pragma unroll
  for (int e = 0; e < 8; ++e) v1[e] = (short)tile[j0 + 8 + e][d];
  unsigned short* tp = dt + ((size_t)(b * 512 + tc * 64 + d)) * 512 + tr * 64 + j0;
  *(short8*)tp = v0;
  *(short8*)(tp + 8) = v1;
}

// ---------------- K0b: Xm_p = bf16(X .* wM_p) ----------------
__global__ __launch_bounds__(256) void k0_xm(
    const float* __restrict__ A, const float* __restrict__ Bm,
    const float* __restrict__ w0, const float* __restrict__ w1, const float* __restrict__ w2,
    unsigned short* __restrict__ Xm0, unsigned short* __restrict__ Xm1,
    unsigned short* __restrict__ Xm2) {
  unsigned int idx = blockIdx.x * 256 + threadIdx.x;   // 786432 threads
  size_t e0 = (size_t)idx * 8;
  int k0 = (int)(e0 & 511);
  unsigned int ri = (unsigned int)(e0 >> 9);  // p*4096 + b*512 + i
  int p = ri >> 12;
  unsigned int rowi = ri & 4095;
  const float* X = (p == 2) ? Bm : A;
  const float* wm = ((p == 0) ? w0 : (p == 1) ? w1 : w2) + 2 * HH;
  const float* xp = X + (size_t)rowi * 512 + k0;
  float4 a = *(const float4*)xp, b4 = *(const float4*)(xp + 4);
  float4 wa = *(const float4*)(wm + k0), wb = *(const float4*)(wm + k0 + 4);
  short8 o;
  o[0] = (short)f2bf(a.x * wa.x); o[1] = (short)f2bf(a.y * wa.y);
  o[2] = (short)f2bf(a.z * wa.z); o[3] = (short)f2bf(a.w * wa.w);
  o[4] = (short)f2bf(b4.x * wb.x); o[5] = (short)f2bf(b4.y * wb.y);
  o[6] = (short)f2bf(b4.z * wb.z); o[7] = (short)f2bf(b4.w * wb.w);
  unsigned short* op = ((p == 0) ? Xm0 : (p == 1) ? Xm1 : Xm2) + (size_t)rowi * 512 + k0;
  *(short8*)op = o;
}

// ---------------- K1: row/col bias terms (each row read once, 2 dots) ----------------
__global__ __launch_bounds__(256) void k1_terms(
    const float* __restrict__ A, const float* __restrict__ Bm, const float* __restrict__ C,
    const float* __restrict__ w0, const float* __restrict__ w1, const float* __restrict__ w2,
    float* __restrict__ rowterm, float* __restrict__ colterm) {
  int tid = threadIdx.x;
  int wave = blockIdx.x * 4 + (tid >> 6);   // 0..12287
  int lane = tid & 63;
  int m = wave >> 12;
  int rem = wave & 4095;
  int b = rem >> 9, i = rem & 511;
  const float* src = (m == 0) ? A : (m == 1 ? Bm : C);
  const float *wva, *wvb;
  float *da, *db;
  if (m == 0) {
    wva = w0;      wvb = w1;
    da = rowterm + (0 * BB + b) * LL + i;  db = rowterm + (1 * BB + b) * LL + i;
  } else if (m == 1) {
    wva = w0 + HH; wvb = w2;
    da = colterm + (0 * BB + b) * LL + i;  db = rowterm + (2 * BB + b) * LL + i;
  } else {
    wva = w1 + HH; wvb = w2 + HH;
    da = colterm + (1 * BB + b) * LL + i;  db = colterm + (2 * BB + b) * LL + i;
  }
  const float* row = src + ((size_t)b * LL + i) * HH;
  float a1 = 0.f, a2 = 0.f;
#pragma unroll
  for (int t = 0; t < 8; ++t) {
    float x = row[t * 64 + lane];
    a1 += x * wva[t * 64 + lane];
    a2 += x * wvb[t * 64 + lane];
  }
#pragma unroll
  for (int off = 32; off; off >>= 1) {
    a1 += __shfl_xor(a1, off, 64);
    a2 += __shfl_xor(a2, off, 64);
  }
  if (lane == 0) { *da = a1; *db = a2; }
}

// ---------------- K2: fused MFMA pair-attention, high-occupancy retile ----------------
// 16 rows/block, 768 blocks x 512 threads (8 waves, each a 64-col slice).
// S in registers; softmax via 8-wave LDS combine; P through 16KB swizzled LDS.
__global__ __launch_bounds__(512) void k2_mfma(
    const unsigned short* __restrict__ Xm0, const unsigned short* __restrict__ Xm1,
    const unsigned short* __restrict__ Xm2,
    const unsigned short* __restrict__ Bn, const unsigned short* __restrict__ Cn,
    const unsigned short* __restrict__ Bt, const unsigned short* __restrict__ Ct,
    const float* __restrict__ A, const float* __restrict__ Bm,
    const float* __restrict__ rowterm, const float* __restrict__ colterm,
    float* __restrict__ mrow, float* __restrict__ out) {
  __shared__ unsigned short P_lds[16 * 512];
  __shared__ float sm_m[8 * 16];
  __shared__ float sm_l[8 * 16];

  int tid = threadIdx.x;
  int bid = blockIdx.x;
  int p = bid >> 8;            // 3
  int rem = bid & 255;
  int b = rem >> 5;            // 8
  int rb = rem & 31;           // 32 row-groups of 16
  int i0 = rb * 16;

  const unsigned short* Xmp = (p == 0) ? Xm0 : ((p == 1) ? Xm1 : Xm2);
  const unsigned short* Yn  = (p == 0) ? Bn : Cn;
  const unsigned short* Yt  = (p == 0) ? Bt : Ct;
  const float* X = (p == 2) ? Bm : A;

  int wc = tid >> 6;           // wave 0..7 -> 64-col slice
  int lane = tid & 63;
  int n16 = lane & 15, q = lane >> 4;

  int arow = i0 + n16;
  const unsigned short* ap = Xmp + ((size_t)(b * LL + arow)) * HH;

  floatx4 acc[4] = {};

  // ---- Phase 1: S = Xm @ Yn^T (cols wc*64 .. wc*64+63) ----
#pragma unroll 1
  for (int kt = 0; kt < 4; ++kt) {
    short8 af[4];
#pragma unroll
    for (int kc = 0; kc < 4; ++kc)
      af[kc] = *(const short8*)(ap + kt * 128 + kc * 32 + q * 8);
#pragma unroll
    for (int kc = 0; kc < 4; ++kc) {
      int k0 = kt * 128 + kc * 32 + q * 8;
#pragma unroll
      for (int f = 0; f < 4; ++f) {
        int col = wc * 64 + f * 16 + n16;
        short8 bf = *(const short8*)(Yn + ((size_t)(b * LL + col)) * HH + k0);
        acc[f] = __builtin_amdgcn_mfma_f32_16x16x32_bf16(af[kc], bf, acc[f], 0, 0, 0);
      }
    }
  }

  // ---- Softmax: per-wave 64-col stats + 8-wave LDS combine ----
  float rt[4], rinv[4], ctv[4], mh[4];
  {
    const float* rtp = rowterm + (p * BB + b) * LL + i0 + q * 4;
#pragma unroll
    for (int r = 0; r < 4; ++r) rt[r] = rtp[r];
    const float* ctp = colterm + (p * BB + b) * LL;
#pragma unroll
    for (int f = 0; f < 4; ++f) ctv[f] = ctp[wc * 64 + f * 16 + n16];
  }
#pragma unroll
  for (int r = 0; r < 4; ++r) {
    float m = -1e30f;
#pragma unroll
    for (int f = 0; f < 4; ++f) {
      float v = acc[f][r] + rt[r] + ctv[f];
      acc[f][r] = v;
      m = fmaxf(m, v);
    }
    m = fmaxf(m, __shfl_xor(m, 1, 64));
    m = fmaxf(m, __shfl_xor(m, 2, 64));
    m = fmaxf(m, __shfl_xor(m, 4, 64));
    m = fmaxf(m, __shfl_xor(m, 8, 64));
    mh[r] = m;
  }
  if (n16 == 0) {
#pragma unroll
    for (int r = 0; r < 4; ++r) sm_m[wc * 16 + q * 4 + r] = mh[r];
  }
  __syncthreads();
  float ml[4];
#pragma unroll
  for (int r = 0; r < 4; ++r) {
    float m = mh[r];
#pragma unroll
    for (int k = 0; k < 8; ++k) m = fmaxf(m, sm_m[k * 16 + q * 4 + r]);
    mh[r] = m;
    float l = 0.f;
#pragma unroll
    for (int f = 0; f < 4; ++f) {
      float pv = __expf(acc[f][r] - m);
      acc[f][r] = pv;
      l += pv;
    }
    l += __shfl_xor(l, 1, 64);
    l += __shfl_xor(l, 2, 64);
    l += __shfl_xor(l, 4, 64);
    l += __shfl_xor(l, 8, 64);
    ml[r] = l;
  }
  if (n16 == 0) {
#pragma unroll
    for (int r = 0; r < 4; ++r) sm_l[wc * 16 + q * 4 + r] = ml[r];
    if (wc == 0) {
#pragma unroll
      for (int r = 0; r < 4; ++r)
        mrow[(p * BB + b) * LL + i0 + q * 4 + r] = mh[r];
    }
  }
  __syncthreads();
#pragma unroll
  for (int r = 0; r < 4; ++r) {
    float lf = 0.f;
#pragma unroll
    for (int k = 0; k < 8; ++k) lf += sm_l[k * 16 + q * 4 + r];
    rinv[r] = 1.f / lf;
  }

  // ---- P -> LDS (bf16, unnormalized, XOR-swizzled 8-short chunks) ----
#pragma unroll
  for (int f = 0; f < 4; ++f) {
    int c = wc * 8 + f * 2 + (n16 >> 3);
#pragma unroll
    for (int r = 0; r < 4; ++r) {
      int row = q * 4 + r;
      int pc = c ^ (row & 7);
      P_lds[row * 512 + pc * 8 + (n16 & 7)] = f2bf(acc[f][r]);
    }
  }
  __syncthreads();

  // ---- Phase 2: O = P @ Y (B from Yt), d in wc's 64-col slice ----
  int secoff, colbase;
  if      (p == 0) { secoff = 0;   colbase = 512;  }
  else if (p == 1) { secoff = 0;   colbase = 1024; }
  else             { secoff = 512; colbase = 1024; }

  int prow = n16;
  floatx4 oacc[4] = {};
#pragma unroll 1
  for (int kj = 0; kj < 16; ++kj) {
    int cj = kj * 4 + q;
    int pc = cj ^ (prow & 7);
    short8 a = *(const short8*)&P_lds[prow * 512 + pc * 8];
    int j0 = kj * 32 + q * 8;
#pragma unroll
    for (int f = 0; f < 4; ++f) {
      int d = wc * 64 + f * 16 + n16;
      short8 bf = *(const short8*)(Yt + ((size_t)(b * LL + d)) * HH + j0);
      oacc[f] = __builtin_amdgcn_mfma_f32_16x16x32_bf16(a, bf, oacc[f], 0, 0, 0);
    }
  }
#pragma unroll
  for (int f = 0; f < 4; ++f) {
    int d = wc * 64 + f * 16 + n16;
#pragma unroll
    for (int r = 0; r < 4; ++r) {
      int ig = i0 + q * 4 + r;
      float val = oacc[f][r] * rinv[r];
      size_t ob = ((size_t)b * 1536 + secoff + ig) * 2560;
      out[ob + colbase + d] = val;
      out[ob + colbase + 1024 + d] = X[((size_t)b * LL + ig) * HH + d] * val;
    }
  }
}

// ---------------- K3: beta softmax + weighted row-sum (192 blocks) ----------------
__global__ __launch_bounds__(256) void k3_beta(
    const float* __restrict__ A, const float* __restrict__ Bm,
    const float* __restrict__ mrow, float* __restrict__ vvec) {
  __shared__ float red[256];
  __shared__ float beta[LL];
  __shared__ float s_inv;
  int blk = blockIdx.x;           // 192
  int p = blk >> 6;
  int rem2 = blk & 63;
  int b = rem2 >> 3;
  int dch = rem2 & 7;
  int tid = threadIdx.x;
  const float* m = mrow + (p * BB + b) * LL;
  red[tid] = fmaxf(m[tid], m[tid + 256]);
  __syncthreads();
  for (int off = 128; off; off >>= 1) {
    if (tid < off) red[tid] = fmaxf(red[tid], red[tid + off]);
    __syncthreads();
  }
  float mx = red[0];
  __syncthreads();
  float e0 = __expf(m[tid] - mx), e1 = __expf(m[tid + 256] - mx);
  beta[tid] = e0; beta[tid + 256] = e1;
  red[tid] = e0 + e1;
  __syncthreads();
  for (int off = 128; off; off >>= 1) {
    if (tid < off) red[tid] += red[tid + off];
    __syncthreads();
  }
  if (tid == 0) s_inv = 1.f / red[0];
  __syncthreads();
  const float* Xb = ((p == 2) ? Bm : A) + (size_t)b * LL * HH;
  int d = dch * 64 + (tid & 63);
  int ig = tid >> 6;
  float acc = 0.f;
  for (int i = ig * 128; i < ig * 128 + 128; ++i)
    acc += beta[i] * Xb[(size_t)i * HH + d];
  red[tid] = acc;
  __syncthreads();
  if (tid < 64) {
    float s = red[tid] + red[tid + 64] + red[tid + 128] + red[tid + 192];
    vvec[(p * BB + b) * HH + dch * 64 + tid] = s * s_inv;
  }
}

// ---------------- K4: finalize, float4, only needed slices ----------------
__global__ __launch_bounds__(256) void k4_finalize(
    const float* __restrict__ A, const float* __restrict__ Bm, const float* __restrict__ C,
    const float* __restrict__ vvec, float* __restrict__ out) {
  unsigned int idx = blockIdx.x * 256 + threadIdx.x;   // 4718592 threads
  int f4 = idx & 127;
  int i  = (idx >> 7) & 511;
  unsigned int ub = idx >> 16;
  unsigned int u = ub % 9;
  unsigned int b = ub / 9;
  int sec, slice;
  if (u == 0)      { sec = 0; slice = 0; }
  else if (u <= 3) { sec = 1; slice = (u == 1) ? 0 : (u == 2 ? 1 : 3); }
  else             { sec = 2; slice = (int)u - 4; }
  int cc = f4 * 4;
  const float* enc = sec == 0 ? A : (sec == 1 ? Bm : C);
  float4 e = *(const float4*)(enc + ((size_t)b * LL + i) * HH + cc);
  float4 val;
  if (slice == 0) val = e;
  else {
    int vp = (sec == 1) ? 0 : ((slice == 1 || slice == 3) ? 1 : 2);
    float4 v = *(const float4*)(vvec + (vp * BB + b) * HH + cc);
    if (slice <= 2) val = v;
    else { val.x = e.x * v.x; val.y = e.y * v.y; val.z = e.z * v.z; val.w = e.w * v.w; }
  }
  *(float4*)(out + ((size_t)b * 1536 + sec * 512 + i) * 2560 + slice * 512 + cc) = val;
}

extern "C" void kernel_launch(void* const* d_in, const int* in_sizes, int n_in,
                              void* d_out, int out_size, void* d_ws, size_t ws_size,
                              hipStream_t stream) {
  const float* A  = (const float*)d_in[0];
  const float* Bm = (const float*)d_in[1];
  const float* C  = (const float*)d_in[2];
  const float* w0 = (const float*)d_in[3];
  const float* w1 = (const float*)d_in[4];
  const float* w2 = (const float*)d_in[5];
  float* out = (float*)d_out;

  float* wsf = (float*)d_ws;
  float* rowterm = wsf;
  float* colterm = wsf + 12288;
  float* mrow    = wsf + 24576;
  float* vvec    = wsf + 36864;
  unsigned short* wss = (unsigned short*)(wsf + 49152);
  const size_t MSZ = (size_t)BB * LL * HH;     // 2,097,152
  unsigned short* Bn  = wss;
  unsigned short* Cn  = wss + MSZ;
  unsigned short* Bt  = wss + 2 * MSZ;
  unsigned short* Ct  = wss + 3 * MSZ;
  unsigned short* Xm0 = wss + 4 * MSZ;
  unsigned short* Xm1 = wss + 5 * MSZ;
  unsigned short* Xm2 = wss + 6 * MSZ;

  k0_conv<<<1024, 256, 0, stream>>>(Bm, C, Bn, Cn, Bt, Ct);
  k0_xm<<<3072, 256, 0, stream>>>(A, Bm, w0, w1, w2, Xm0, Xm1, Xm2);
  k1_terms<<<3072, 256, 0, stream>>>(A, Bm, C, w0, w1, w2, rowterm, colterm);
  k2_mfma<<<768, 512, 0, stream>>>(Xm0, Xm1, Xm2, Bn, Cn, Bt, Ct, A, Bm,
                                   rowterm, colterm, mrow, out);
  k3_beta<<<192, 256, 0, stream>>>(A, Bm, mrow, vvec);
  k4_finalize<<<18432, 256, 0, stream>>>(A, Bm, C, vvec, out);
}